// Round 1
// baseline (112.548 us; speedup 1.0000x reference)
//
#include <hip/hip_runtime.h>
#include <math.h>

#define KE 14.3996f
#define R_MAX 6.0f

// P8 exact path: short4 {qx,qy,qz (step 1/512), Z} — validated R5-R10, absmax 0.0
#define PSCALE 512.0f
#define INV_PS2 (1.0f / (512.0f * 512.0f))

// ws float-index layout: [0] ae [1] 1/an [2] pre  [3..6] coeffs  [7..10] exps
// [16..79] powtab.  Byte offset 512+: XY, X4, P8 tables.
#define WS_POW_F 16

// Screen (conservative-exact: discard ==> |delta|>=6 ==> cutoff==0):
//  XY byte: 4-bit bins/axis, width 2 over [-16,16], clamped.
//    discard iff |dbin|>=4 on x or y (non-clamp min gap 2(|db|-1)>=6; clamp grows it).
//  Z screen dropped (R11): cost 2 ds_read_u8 + ~10 VALU on ALL edges to cut
//  only ~2.3% of pushes — net negative; freed 50KB LDS funds QCAP=128.

typedef short s4 __attribute__((ext_vector_type(4)));

__device__ __forceinline__ float softplus_f(float x) { return log1pf(expf(x)); }

__device__ __forceinline__ int bin2(float x) {
    int b = (int)floorf((x + 16.0f) * 0.5f);
    return min(max(b, 0), 15);
}

// Fused scalar prep + per-atom tables (one launch).
__global__ __launch_bounds__(256) void atom_prep(
        const float* __restrict__ R, const int* __restrict__ Z,
        const float* __restrict__ a_exp, const float* __restrict__ a_num,
        const float* __restrict__ coef, const float* __restrict__ expo,
        const float* __restrict__ rs,
        unsigned char* __restrict__ XY, unsigned char* __restrict__ X4,
        s4* __restrict__ P8,
        float* __restrict__ ws, float* __restrict__ out, int nA) {
    const int i = blockIdx.x * 256 + threadIdx.x;
    if (blockIdx.x == 0) {
        const int t = threadIdx.x;
        const float ae = softplus_f(a_exp[0]);
        if (t == 0) {
            ws[0] = ae;
            ws[1] = 1.0f / softplus_f(a_num[0]);
            ws[2] = 0.5f * KE * softplus_f(rs[0]);
            out[0] = 0.0f;   // d_out poisoned 0xAA before every timed call
        }
        if (t < 4) { ws[3 + t] = softplus_f(coef[t]); ws[7 + t] = softplus_f(expo[t]); }
        if (t < 64) ws[WS_POW_F + t] = (t > 0) ? expf(ae * logf((float)t)) : 0.0f;
    }
    if (i < nA) {
        const float x = R[3 * i], y = R[3 * i + 1], z = R[3 * i + 2];
        s4 v;
        v.x = (short)lrintf(x * PSCALE);
        v.y = (short)lrintf(y * PSCALE);
        v.z = (short)lrintf(z * PSCALE);
        v.w = (short)Z[i];
        P8[i] = v;
        XY[i] = (unsigned char)(bin2(x) | (bin2(y) << 4));
    }
    if ((i & 1) == 0 && i < nA) {        // even thread packs 2 atoms' x-nibbles
        unsigned int xb = (unsigned int)bin2(R[3 * i]);
        if (i + 1 < nA) xb |= ((unsigned int)bin2(R[3 * (i + 1)])) << 4;
        X4[i >> 1] = (unsigned char)xb;
    }
}

// exact per-edge term (validated R5-R10: absmax 0.0)
__device__ __forceinline__ float edge_term(const s4* __restrict__ P8, int i, int j,
                                           const float* __restrict__ R,
                                           const float* __restrict__ spow,
                                           float inv_an,
                                           float c0, float c1, float c2, float c3,
                                           float e0, float e1, float e2, float e3) {
    const s4 pa = P8[i];
    const s4 pb = P8[j];
    const float dx = (float)(pb.x - pa.x);
    const float dy = (float)(pb.y - pa.y);
    const float dz = (float)(pb.z - pa.z);
    const float dr2 = (dx * dx + dy * dy + dz * dz) * INV_PS2;
    if (dr2 >= R_MAX * R_MAX) return 0.0f;   // screen conservative: exact re-check
    float dr;
    if (dr2 < 0.1225f) {
        // rare: 1/dr^2 sensitivity — recompute from exact fp32 R
        const float ax = R[3 * i], ay = R[3 * i + 1], az = R[3 * i + 2];
        const float bx = R[3 * j], by = R[3 * j + 1], bz = R[3 * j + 2];
        const float fx = bx - ax, fy = by - ay, fz = bz - az;
        dr = fmaxf(__fsqrt_rn(fx * fx + fy * fy + fz * fz), 0.02f);
    } else {
        dr = __fsqrt_rn(dr2);
    }
    const float ppa = spow[(int)pa.w] + spow[(int)pb.w];
    const float dist = dr * ppa * inv_an;
    const float f = c0 * __expf(-e0 * dist) + c1 * __expf(-e1 * dist)
                  + c2 * __expf(-e2 * dist) + c3 * __expf(-e3 * dist);
    const float cut = 0.5f * (__cosf((float)M_PI / R_MAX * dr) + 1.0f);
    return (float)pa.w * (float)pb.w / dr * f * cut;
}

// QCAP=128: count<=63 before each push; push<=64 -> peak<=127; pop always a
// FULL 64-lane batch (R10's >=32 pops averaged ~75% lane utilization).
#define QCAP 128

#define PUSH_POP(k_, iv, jv)                                                    \
    {                                                                           \
        const bool _k = (k_);                                                   \
        const unsigned long long _m = __ballot(_k);                             \
        if (_k) {                                                               \
            const int _pfx = (int)__builtin_amdgcn_mbcnt_hi(                    \
                (unsigned int)(_m >> 32),                                       \
                __builtin_amdgcn_mbcnt_lo((unsigned int)_m, 0u));               \
            buf[wv][count + _pfx] = ((unsigned long long)(unsigned int)(iv) << 32) \
                            | (unsigned int)(jv);                               \
        }                                                                       \
        count += __popcll(_m);                                                  \
        if (count >= 64) {       /* pop one full-wave batch, no barriers */     \
            count -= 64;                                                        \
            const unsigned long long _p = buf[wv][count + lane];                \
            local += edge_term(P8, (int)(_p >> 32), (int)(_p & 0xffffffffu),    \
                               R, spow, inv_an, c0,c1,c2,c3, e0,e1,e2,e3);      \
        }                                                                       \
    }

// Tail edges load i=j=0 -> self-pair -> dropped by (i!=j); exact either way.
#define LOADQ(g_, ii_, jj_)                                                     \
    {                                                                           \
        const int _b = ((g_) << 8) + (lane << 2);                               \
        if (_b + 3 < nE) {                                                      \
            ii_ = *(const int4*)(idx_i + _b);                                   \
            jj_ = *(const int4*)(idx_j + _b);                                   \
        } else {                                                                \
            ii_.x = ii_.y = ii_.z = ii_.w = 0;                                  \
            jj_.x = jj_.y = jj_.z = jj_.w = 0;                                  \
            if (_b < nE)     { ii_.x = idx_i[_b];     jj_.x = idx_j[_b]; }      \
            if (_b + 1 < nE) { ii_.y = idx_i[_b + 1]; jj_.y = idx_j[_b + 1]; }  \
            if (_b + 2 < nE) { ii_.z = idx_i[_b + 2]; jj_.z = idx_j[_b + 2]; }  \
        }                                                                       \
    }

// 4 edges/lane per iteration, int4 idx loads (16B coalesced — G13 sweet spot).
// Depth-1 software pipeline: next group's idx loads issue BEFORE the current
// group's screen/push work, hiding global-load latency (4 waves/SIMD only).
#define EDGE_BODY                                                               \
    const float inv_an = ssc[1];                                                \
    const float c0 = ssc[3], c1 = ssc[4], c2 = ssc[5], c3 = ssc[6];             \
    const float e0 = ssc[7], e1 = ssc[8], e2 = ssc[9], e3 = ssc[10];            \
    float local = 0.0f;                                                         \
    int count = 0;                                                              \
    const int wpb = blockDim.x >> 6;                                            \
    const int nW = gridDim.x * wpb;                                             \
    const int nG = (nE + 255) >> 8;                                             \
    int g = blockIdx.x * wpb + wv;                                              \
    if (g < nG) {                                                               \
        int4 ii, jj;                                                            \
        LOADQ(g, ii, jj)                                                        \
        while (true) {                                                          \
            const int gn = g + nW;                                              \
            int4 iin, jjn;                                                      \
            if (gn < nG) LOADQ(gn, iin, jjn)                                    \
            const bool k0 = (ii.x != jj.x) && keepf(ii.x, jj.x);                \
            const bool k1 = (ii.y != jj.y) && keepf(ii.y, jj.y);                \
            const bool k2 = (ii.z != jj.z) && keepf(ii.z, jj.z);                \
            const bool k3 = (ii.w != jj.w) && keepf(ii.w, jj.w);                \
            PUSH_POP(k0, ii.x, jj.x)                                            \
            PUSH_POP(k1, ii.y, jj.y)                                            \
            PUSH_POP(k2, ii.z, jj.z)                                            \
            PUSH_POP(k3, ii.w, jj.w)                                            \
            if (gn >= nG) break;                                                \
            g = gn; ii = iin; jj = jjn;                                         \
        }                                                                       \
    }                                                                           \
    while (count > 0) {          /* drain */                                    \
        const int k = (count < 64) ? count : 64;                                \
        count -= k;                                                             \
        if (lane < k) {                                                         \
            const unsigned long long p = buf[wv][count + lane];                 \
            local += edge_term(P8, (int)(p >> 32), (int)(p & 0xffffffffu),      \
                               R, spow, inv_an, c0,c1,c2,c3, e0,e1,e2,e3);      \
        }                                                                       \
    }                                                                           \
    for (int off = 32; off > 0; off >>= 1) local += __shfl_down(local, off);    \
    if (lane == 0) wsum[wv] = local;                                            \
    __syncthreads();                                                            \
    if (threadIdx.x == 0) {                                                     \
        float s = 0.0f;                                                         \
        for (int w = 0; w < (int)(blockDim.x >> 6); ++w) s += wsum[w];          \
        atomicAdd(out, s * ssc[2]);                                             \
    }

// BIG: XY byte table (100 KB) in dynamic LDS; keep ~7.8%.
__global__ __launch_bounds__(1024) void zbl_big(
        const unsigned char* __restrict__ XY,
        const s4* __restrict__ P8, const float* __restrict__ R,
        const int* __restrict__ idx_i, const int* __restrict__ idx_j,
        const float* __restrict__ ws, float* __restrict__ out, int nE, int nA) {
    extern __shared__ unsigned char lds[];
    __shared__ unsigned long long buf[16][QCAP];
    __shared__ float spow[64];
    __shared__ float ssc[11];
    __shared__ float wsum[16];
    const int tid = threadIdx.x, lane = tid & 63, wv = tid >> 6;
    const int xyPad = (nA + 15) & ~15;
    for (int off = tid * 16; off < xyPad; off += 1024 * 16)
        *(int4*)(lds + off) = *(const int4*)(XY + off);
    if (tid < 64) spow[tid] = ws[WS_POW_F + tid];
    if (tid < 11) ssc[tid] = ws[tid];
    __syncthreads();

    auto keepf = [&](int i, int j) -> bool {
        const int ci = lds[i], cj = lds[j];
        // |a-b|<=3  <=>  (unsigned)(a-b+3) <= 6  (branch-free, no abs)
        return ((unsigned)((ci & 15) - (cj & 15) + 3) <= 6u)
             & ((unsigned)((ci >> 4) - (cj >> 4) + 3) <= 6u);
    };
    EDGE_BODY
}

// SAFE (<=64 KB): 4-bit x-axis nibble table (50 KB); keep ~38%; 2 blocks/CU.
__global__ __launch_bounds__(1024) void zbl_safe(
        const unsigned char* __restrict__ X4,
        const s4* __restrict__ P8, const float* __restrict__ R,
        const int* __restrict__ idx_i, const int* __restrict__ idx_j,
        const float* __restrict__ ws, float* __restrict__ out, int nE, int nA) {
    extern __shared__ unsigned char lds[];
    __shared__ unsigned long long buf[16][QCAP];
    __shared__ float spow[64];
    __shared__ float ssc[11];
    __shared__ float wsum[16];
    const int tid = threadIdx.x, lane = tid & 63, wv = tid >> 6;
    const int x4Pad = (((nA + 1) >> 1) + 15) & ~15;
    for (int off = tid * 16; off < x4Pad; off += 1024 * 16)
        *(int4*)(lds + off) = *(const int4*)(X4 + off);
    if (tid < 64) spow[tid] = ws[WS_POW_F + tid];
    if (tid < 11) ssc[tid] = ws[tid];
    __syncthreads();

    auto keepf = [&](int i, int j) -> bool {
        const int bi = (lds[i >> 1] >> ((i & 1) * 4)) & 15;
        const int bj = (lds[j >> 1] >> ((j & 1) * 4)) & 15;
        return (unsigned)(bi - bj + 3) <= 6u;
    };
    EDGE_BODY
}

extern "C" void kernel_launch(void* const* d_in, const int* in_sizes, int n_in,
                              void* d_out, int out_size, void* d_ws, size_t ws_size,
                              hipStream_t stream) {
    const float* R     = (const float*)d_in[0];
    const int*   Z     = (const int*)d_in[1];
    const int*   idx   = (const int*)d_in[2];
    const float* a_exp = (const float*)d_in[3];
    const float* a_num = (const float*)d_in[4];
    const float* coef  = (const float*)d_in[5];
    const float* expo  = (const float*)d_in[6];
    const float* rs    = (const float*)d_in[7];

    float* out = (float*)d_out;
    float* wsf = (float*)d_ws;
    unsigned char* wsb = (unsigned char*)d_ws;

    const int nA = in_sizes[0] / 3;
    const int nE = in_sizes[2] / 2;
    const int* idx_i = idx;
    const int* idx_j = idx + nE;

    const int xyPad = (nA + 15) & ~15;
    const int nibPad = (((nA + 1) >> 1) + 15) & ~15;
    unsigned char* XY = wsb + 512;
    unsigned char* X4 = XY + xyPad;
    s4* P8 = (s4*)(X4 + nibPad);

    atom_prep<<<(nA + 255) / 256, 256, 0, stream>>>(R, Z, a_exp, a_num, coef,
                                                    expo, rs, XY, X4, P8,
                                                    wsf, out, nA);

    // Deterministic per-device path selection (same work every call).
    const int dynBig = xyPad;                   // 100 KB for nA=100K
    int dev = 0;
    (void)hipGetDevice(&dev);
    int maxShm = 0;
    (void)hipDeviceGetAttribute(&maxShm, hipDeviceAttributeMaxSharedMemoryPerBlock, dev);
    hipFuncAttributes fa{};
    (void)hipFuncGetAttributes(&fa, (const void*)zbl_big);
    const int staticLds = 16 * QCAP * 8 + 256 + 48 + 64 + 64;   // ~16.8 KB
    const bool big = (maxShm >= dynBig + staticLds) ||
                     (fa.maxDynamicSharedSizeBytes >= dynBig);

    if (big) {
        (void)hipFuncSetAttribute((const void*)zbl_big,
                                  hipFuncAttributeMaxDynamicSharedMemorySize, dynBig);
        zbl_big<<<256, 1024, dynBig, stream>>>(XY, P8, R, idx_i, idx_j,
                                               wsf, out, nE, nA);
    } else {
        zbl_safe<<<512, 1024, nibPad, stream>>>(X4, P8, R, idx_i, idx_j,
                                                wsf, out, nE, nA);
    }
}